// Round 20
// baseline (130.000 us; speedup 1.0000x reference)
//
#include <hip/hip_runtime.h>
#include <math.h>

#define BB 16
#define NN 24564
#define CC 81
#define KK 50
#define MT 200
#define NROWS (BB * NN)        // 393024 = 12282 waves x 32 rows exactly
#define CAND_CAP 512           // class c>0: ~123+-11 (35 sigma); class 0: ~389+-20 (6 sigma)
#define T1 0.995f              // tier-1 threshold, classes 1..80
#define T1C0 0.975f            // tier-1 threshold, class 0 (masked-column yield is lower)
#define TIER_W 0.02f
#define PADI 32                // ints per counter slot (128B padding)
#define CHUNK 128              // k_nms box-staging chunk
#define WBUF 128               // per-wave candidate buffer (expected ~13; overflow flushes)

typedef unsigned long long u64;
typedef unsigned int u32;

__device__ __forceinline__ u64 pack_cand(float s, int n) {
    return ((u64)__float_as_uint(s) << 32) | (u32)(~(u32)n);
}

// descending bitonic sort of P u64 keys in LDS, NT threads
template <int P, int NT>
__device__ __forceinline__ void bitonic_desc(u64* a, int tid) {
    for (int k = 2; k <= P; k <<= 1) {
        for (int j = k >> 1; j > 0; j >>= 1) {
            for (int i = tid; i < P; i += NT) {
                int l = i ^ j;
                if (l > i) {
                    u64 x = a[i], y = a[l];
                    bool sw = (i & k) ? (x > y) : (x < y);
                    if (sw) { a[i] = y; a[l] = x; }
                }
            }
            __syncthreads();
        }
    }
}

// ---------------------------------------------------------------------------
// Kernel 0: zero the 1296 used counter slots.
// ---------------------------------------------------------------------------
__global__ __launch_bounds__(256) void k_zero(int* __restrict__ cnt_g)
{
    int i = blockIdx.x * 256 + threadIdx.x;
    if (i < BB * CC) cnt_g[i * PADI] = 0;
}

// ---------------------------------------------------------------------------
// Kernel 1: fused label filter + box decode. One WAVE per 32 rows.
// R20: (a) MLP deepened to 16-row groups (32 loads in flight) -- halves the
// per-group full-latency stalls; (b) box decode fused: lanes<32 issue their
// row's priors/deltas loads at kernel ENTRY (hidden under label phase) and
// decode from registers at the end. Logic bit-identical to R19+R4 (proven).
// ---------------------------------------------------------------------------
__global__ __launch_bounds__(256) void k_filter(
    const float* __restrict__ labels, const float* __restrict__ deltas,
    const float* __restrict__ priors, unsigned char* __restrict__ bg,
    float4* __restrict__ boxes, int* __restrict__ cnt_g,
    u64* __restrict__ cand_g)
{
    __shared__ u64 sbuf[4][WBUF];
    int tid = threadIdx.x;
    int w = tid >> 6, lane = tid & 63;
    int wid = (blockIdx.x * 256 + tid) >> 6;
    int base = wid * 32;                      // 32 consecutive rows per wave
    if (base >= NROWS) return;                // uniform per wave

    // box-decode prefetch (lanes<32, one row each) -- hides under label phase
    int rdec = base + (lane & 31);
    int bdec = rdec / NN;
    int ndec = rdec - bdec * NN;
    float4 pr, dl;
    if (lane < 32) {
        pr = ((const float4*)priors)[ndec];
        dl = ((const float4*)deltas)[rdec];
    }

    u64* buf = sbuf[w];
    u64 ltmask = (lane == 63) ? 0x7FFFFFFFFFFFFFFFull : ((1ull << lane) - 1ull);
    int cnt = 0;                              // wave-uniform queue count

    u32 bgbits = 0;
    for (int g = 0; g < 2; ++g) {
        int r0 = base + g * 16;
        float va[16], vb[16];
        // load phase: 32 independent loads in flight, no branches
        #pragma unroll
        for (int j = 0; j < 16; ++j) {
            const float* L = labels + (size_t)(r0 + j) * CC;
            va[j] = L[lane];
            vb[j] = (lane < CC - 64) ? L[64 + lane] : -1.0f;
        }
        // process phase: register ops + ballots + rare LDS queue writes
        #pragma unroll
        for (int j = 0; j < 16; ++j) {
            int r = r0 + j;
            float L0 = __int_as_float(
                __builtin_amdgcn_readfirstlane(__float_as_int(va[j])));
            bool gt = (va[j] > L0) || (vb[j] > L0);   // vb=-1 for lanes>=17
            bool isbg = (__ballot(gt) == 0ull);       // argmax==0, 1st-idx rule
            bgbits |= (isbg ? 1u : 0u) << (g * 16 + j);
            float th1 = (lane == 0) ? T1C0 : T1;
            bool c1 = !isbg && (va[j] > th1);
            bool c2 = !isbg && (lane < CC - 64) && (vb[j] > T1);
            u64 m1 = __ballot(c1);
            u64 m2 = __ballot(c2);
            if (m1 | m2) {                            // uniform branch
                int tot = (int)(__popcll(m1) + __popcll(m2));
                if (cnt + tot > WBUF) {               // uniform overflow flush
                    for (int i = lane; i < cnt; i += 64) {
                        u64 e = buf[i];
                        float v = __uint_as_float((u32)(e >> 32));
                        u32 lo = (u32)e;
                        int c = (int)((lo >> 19) & 0x7F);
                        int rr = (int)(lo & 0x7FFFF);
                        int b = rr / NN;
                        int n = rr - b * NN;
                        int p = atomicAdd(&cnt_g[(b * CC + c) * PADI], 1);
                        if (p < CAND_CAP)
                            cand_g[(size_t)(b * CC + c) * CAND_CAP + p] =
                                pack_cand(v, n);
                    }
                    cnt = 0;
                }
                if (c1) {
                    int slot = cnt + (int)__popcll(m1 & ltmask);
                    buf[slot] = ((u64)__float_as_uint(va[j]) << 32)
                              | ((u64)lane << 19) | (u32)r;
                }
                if (c2) {
                    int slot = cnt + (int)__popcll(m1)
                             + (int)__popcll(m2 & ltmask);
                    buf[slot] = ((u64)__float_as_uint(vb[j]) << 32)
                              | ((u64)(64 + lane) << 19) | (u32)r;
                }
                cnt += tot;
            }
        }
    }
    // final lane-parallel flush: one atomic instruction per 64 entries
    for (int i = lane; i < cnt; i += 64) {
        u64 e = buf[i];
        float v = __uint_as_float((u32)(e >> 32));
        u32 lo = (u32)e;
        int c = (int)((lo >> 19) & 0x7F);
        int rr = (int)(lo & 0x7FFFF);
        int b = rr / NN;
        int n = rr - b * NN;
        int p = atomicAdd(&cnt_g[(b * CC + c) * PADI], 1);
        if (p < CAND_CAP)
            cand_g[(size_t)(b * CC + c) * CAND_CAP + p] = pack_cand(v, n);
    }
    // coalesced bg write: lane l<8 packs 4 rows' bytes into one u32
    if (lane < 8) {
        u32 wv = 0;
        #pragma unroll
        for (int j = 0; j < 4; ++j)
            wv |= ((bgbits >> (4 * lane + j)) & 1u) << (8 * j);
        *(u32*)(bg + base + 4 * lane) = wv;
    }

    // box decode epilogue (exact numpy op order, FMA-free), from registers
    if (lane < 32) {
        float ph  = __fsub_rn(pr.z, pr.x);
        float pw  = __fsub_rn(pr.w, pr.y);
        float pcy = __fadd_rn(pr.x, __fmul_rn(0.5f, ph));
        float pcx = __fadd_rn(pr.y, __fmul_rn(0.5f, pw));
        float d0 = __fmul_rn(dl.x, 0.1f);
        float d1 = __fmul_rn(dl.y, 0.1f);
        float d2 = __fmul_rn(dl.z, 0.2f);
        float d3 = __fmul_rn(dl.w, 0.2f);
        float cy = __fadd_rn(__fmul_rn(d0, ph), pcy);
        float cx = __fadd_rn(__fmul_rn(d1, pw), pcx);
        float hh = __fmul_rn(expf(d2), ph);
        float ww = __fmul_rn(expf(d3), pw);
        float h2 = __fmul_rn(hh, 0.5f);
        float w2 = __fmul_rn(ww, 0.5f);
        float y1 = fminf(fmaxf(__fsub_rn(cy, h2), 0.0f), 1.0f);
        float x1 = fminf(fmaxf(__fsub_rn(cx, w2), 0.0f), 1.0f);
        float y2 = fminf(fmaxf(__fadd_rn(cy, h2), 0.0f), 1.0f);
        float x2 = fminf(fmaxf(__fadd_rn(cx, w2), 0.0f), 1.0f);
        boxes[rdec] = make_float4(y1, x1, y2, x2);
    }
}

// ---------------------------------------------------------------------------
// Kernel 2: per-(b,c) sorted-scan greedy NMS. 256 threads. (unchanged)
// ---------------------------------------------------------------------------
__global__ __launch_bounds__(256) void k_nms(
    const float* __restrict__ labels, const unsigned char* __restrict__ bg,
    const float4* __restrict__ boxes, const int* __restrict__ cnt_g,
    const u64* __restrict__ cand_g,
    float* __restrict__ out_s, int* __restrict__ out_i)
{
    __shared__ u64 arr[CAND_CAP];
    __shared__ float4 sbox[CHUNK];
    __shared__ float ks[KK];
    __shared__ int   ki[KK];
    __shared__ int s_kept, s_cnt;

    int bc = blockIdx.x, tid = threadIdx.x;
    int b = bc / CC, c = bc - b * CC;
    float thrc = (c == 0) ? T1C0 : T1;
    const float4* bxb = boxes + (size_t)b * NN;

    int gcnt = cnt_g[bc * PADI];
    bool ovf = gcnt > CAND_CAP;
    int cnt0 = ovf ? 0 : gcnt;
    for (int i = tid; i < CAND_CAP; i += 256)
        arr[i] = (i < cnt0) ? cand_g[(size_t)bc * CAND_CAP + i] : 0ull;
    if (tid == 0) { s_kept = 0; s_cnt = cnt0; }
    __syncthreads();

    float4 kb = make_float4(0.f, 0.f, 0.f, 0.f);
    float  ka = 0.0f;
    float hi = ovf ? 1.0001f : thrc;
    float bw = TIER_W;
    bool first = !ovf;

    while (true) {
        if (!first) {
            if (s_kept >= KK || hi <= 0.5f) break;
            float lo = fmaxf(hi - bw, 0.5f);
            if (tid == 0) s_cnt = 0;
            __syncthreads();
            const float* lab = labels + (size_t)b * NN * CC + c;
            const unsigned char* bgb = bg + (size_t)b * NN;
            for (int n = tid; n < NN; n += 256) {
                float v = lab[(size_t)n * CC];
                if (v > lo && v <= hi && v > 0.5f && !bgb[n]) {
                    int p = atomicAdd(&s_cnt, 1);
                    if (p < CAND_CAP) arr[p] = pack_cand(v, n);
                }
            }
            __syncthreads();
            if (s_cnt > CAND_CAP && bw > 1e-7f) {  // band overflow: shrink, retry
                bw *= 0.5f;
                __syncthreads();
                continue;
            }
            int c2 = min(s_cnt, CAND_CAP);
            for (int i = tid; i < CAND_CAP; i += 256)
                if (i >= c2) arr[i] = 0ull;
            hi = lo;
            bw = TIER_W;
            __syncthreads();
        }
        first = false;

        int cs = min(s_cnt, CAND_CAP);
        if (cs <= 128)      bitonic_desc<128, 256>(arr, tid);  // uniform branch
        else if (cs <= 256) bitonic_desc<256, 256>(arr, tid);
        else                bitonic_desc<CAND_CAP, 256>(arr, tid);

        // chunked stage + scan: most blocks finish in the first 128
        for (int ch0 = 0; ch0 < cs; ch0 += CHUNK) {
            if (s_kept >= KK) break;                       // uniform (post-sync)
            int che = min(ch0 + CHUNK, cs);
            for (int i = ch0 + tid; i < che; i += 256) {
                int n = (int)(~(u32)arr[i]);
                if ((u32)n < (u32)NN) sbox[i - ch0] = bxb[n];  // guarded
            }
            __syncthreads();
            if (tid < 64) {                    // wave 0: serial greedy scan
                int kept = s_kept;
                for (int i = ch0; i < che; ++i) {
                    u64 key = arr[i];
                    float sc = __uint_as_float((u32)(key >> 32));
                    int n = (int)(~(u32)key);
                    float4 cb = sbox[i - ch0];
                    float a1 = __fmul_rn(__fsub_rn(cb.z, cb.x), __fsub_rn(cb.w, cb.y));
                    bool sup = false;
                    if (tid < kept) {
                        float iy1 = fmaxf(kb.x, cb.x);
                        float ix1 = fmaxf(kb.y, cb.y);
                        float iy2 = fminf(kb.z, cb.z);
                        float ix2 = fminf(kb.w, cb.w);
                        float ih = fmaxf(__fsub_rn(iy2, iy1), 0.0f);
                        float iw = fmaxf(__fsub_rn(ix2, ix1), 0.0f);
                        float inter = __fmul_rn(ih, iw);
                        float den = __fadd_rn(__fsub_rn(__fadd_rn(ka, a1), inter), 1e-8f);
                        sup = __fdiv_rn(inter, den) > 0.5f;
                    }
                    if (__ballot(sup) == 0ull) {
                        if (tid == kept) { kb = cb; ka = a1; }
                        if (tid == 0)    { ks[kept] = sc; ki[kept] = n; }
                        ++kept;
                        if (kept == KK) break;
                    }
                }
                if (tid == 0) s_kept = kept;
            }
            __syncthreads();
        }
    }

    int kept = min(s_kept, KK);
    for (int k = tid; k < KK; k += 256) {
        out_s[(size_t)bc * KK + k] = (k < kept) ? ks[k] : 0.0f;
        out_i[(size_t)bc * KK + k] = (k < kept) ? ki[k] : 0;
    }
}

// ---------------------------------------------------------------------------
// Kernel 3a: per-(batch, 512-chunk) partial top-200. Grid = BB*8 blocks.
// ---------------------------------------------------------------------------
__global__ __launch_bounds__(256) void k_topk1(
    const float* __restrict__ nms_s, u64* __restrict__ topA)
{
    __shared__ u64 arr[512];
    int bchunk = blockIdx.x;
    int b = bchunk >> 3, ch = bchunk & 7;
    int tid = threadIdx.x;
    int base = ch * 512;
    for (int i = tid; i < 512; i += 256) {
        int fp = base + i;
        u64 v = 0ull;
        if (fp < CC * KK) {
            float s = nms_s[(size_t)b * CC * KK + fp];
            v = ((u64)__float_as_uint(s) << 32) | (u32)(~(u32)fp);
        }
        arr[i] = v;
    }
    __syncthreads();
    bitonic_desc<512, 256>(arr, tid);
    if (tid < MT) topA[(size_t)bchunk * MT + tid] = arr[tid];
}

// ---------------------------------------------------------------------------
// Kernel 3b: per-batch merge of 8x200 -> stable top-200 + output assembly.
// ---------------------------------------------------------------------------
__global__ __launch_bounds__(512) void k_topk2(
    const u64* __restrict__ topA, const int* __restrict__ nms_i,
    const float4* __restrict__ boxes, float* __restrict__ out)
{
    __shared__ u64 arr[2048];
    __shared__ int s_vc;
    int b = blockIdx.x, tid = threadIdx.x;
    for (int i = tid; i < 2048; i += 512)
        arr[i] = (i < 8 * MT) ? topA[(size_t)b * 8 * MT + i] : 0ull;
    if (tid == 0) s_vc = 0;
    __syncthreads();

    bitonic_desc<2048, 512>(arr, tid);

    if (tid < MT) {
        u64 key = arr[tid];
        float sc = __uint_as_float((u32)(key >> 32));
        int fp = (int)(~(u32)key);
        bool valid = sc > 0.0f;
        float4 bb = make_float4(0.f, 0.f, 0.f, 0.f);
        float cls = 0.0f;
        if (valid) {
            int aidx = nms_i[(size_t)b * CC * KK + fp];
            bb = boxes[(size_t)b * NN + aidx];
            cls = (float)(fp / KK);
        }
        ((float4*)out)[(size_t)b * MT + tid] = bb;
        out[(size_t)BB * MT * 4 + (size_t)b * MT + tid] = sc;
        out[(size_t)BB * MT * 5 + (size_t)b * MT + tid] = cls;
        if (valid) atomicAdd(&s_vc, 1);
    }
    __syncthreads();
    if (tid == 0) out[(size_t)BB * MT * 6 + b] = (float)s_vc;
}

// ---------------------------------------------------------------------------
extern "C" void kernel_launch(void* const* d_in, const int* in_sizes, int n_in,
                              void* d_out, int out_size, void* d_ws, size_t ws_size,
                              hipStream_t stream)
{
    const float* deltas = (const float*)d_in[0];
    const float* labels = (const float*)d_in[1];
    const float* priors = (const float*)d_in[2];
    float* out = (float*)d_out;

    char* ws = (char*)d_ws;
    size_t off = 0;
    float4* boxes = (float4*)(ws + off);            off += (size_t)NROWS * 16;
    unsigned char* bg = (unsigned char*)(ws + off); off += ((size_t)NROWS + 127) & ~127ull;
    int* cnt_g = (int*)(ws + off);                  off += (size_t)BB * CC * PADI * 4;
    u64* cand_g = (u64*)(ws + off);                 off += (size_t)BB * CC * CAND_CAP * 8;
    float* nms_s = (float*)(ws + off);              off += (size_t)BB * CC * KK * 4;
    int* nms_i = (int*)(ws + off);                  off += (size_t)BB * CC * KK * 4;
    u64* topA = (u64*)(ws + off);                   off += (size_t)BB * 8 * MT * 8;

    k_zero<<<(BB * CC + 255) / 256, 256, 0, stream>>>(cnt_g);
    k_filter<<<(NROWS / 32 + 3) / 4, 256, 0, stream>>>(labels, deltas, priors,
                                                       bg, boxes, cnt_g, cand_g);
    k_nms<<<BB * CC, 256, 0, stream>>>(labels, bg, boxes, cnt_g, cand_g, nms_s, nms_i);
    k_topk1<<<BB * 8, 256, 0, stream>>>(nms_s, topA);
    k_topk2<<<BB, 512, 0, stream>>>(topA, nms_i, boxes, out);
}

// Round 21
// 128.149 us; speedup vs baseline: 1.0144x; 1.0144x over previous
//
#include <hip/hip_runtime.h>
#include <math.h>

#define BB 16
#define NN 24564
#define CC 81
#define KK 50
#define MT 200
#define NROWS (BB * NN)        // 393024 = 12282 waves x 32 rows exactly
#define CAND_CAP 512           // class c>0: ~123+-11 (35 sigma); class 0: ~389+-20 (6 sigma)
#define T1 0.995f              // tier-1 threshold, classes 1..80
#define T1C0 0.975f            // tier-1 threshold, class 0 (masked-column yield is lower)
#define TIER_W 0.02f
#define PADI 32                // ints per counter slot (128B padding)
#define CHUNK 128              // k_nms box-staging chunk
#define WBUF 128               // per-wave candidate buffer (expected ~13; overflow flushes)

typedef unsigned long long u64;
typedef unsigned int u32;

__device__ __forceinline__ u64 pack_cand(float s, int n) {
    return ((u64)__float_as_uint(s) << 32) | (u32)(~(u32)n);
}

// descending bitonic sort of P u64 keys in LDS, NT threads
template <int P, int NT>
__device__ __forceinline__ void bitonic_desc(u64* a, int tid) {
    for (int k = 2; k <= P; k <<= 1) {
        for (int j = k >> 1; j > 0; j >>= 1) {
            for (int i = tid; i < P; i += NT) {
                int l = i ^ j;
                if (l > i) {
                    u64 x = a[i], y = a[l];
                    bool sw = (i & k) ? (x > y) : (x < y);
                    if (sw) { a[i] = y; a[l] = x; }
                }
            }
            __syncthreads();
        }
    }
}

// ---------------------------------------------------------------------------
// Kernel 0: zero the 1296 used counter slots.
// ---------------------------------------------------------------------------
__global__ __launch_bounds__(256) void k_zero(int* __restrict__ cnt_g)
{
    int i = blockIdx.x * 256 + threadIdx.x;
    if (i < BB * CC) cnt_g[i * PADI] = 0;
}

// ---------------------------------------------------------------------------
// Kernel 1: fused label filter + box decode. One WAVE per 32 rows.
// R22 = R19's proven 8-row-group MLP structure (VGPR < 64-cliff, 8 waves/
// SIMD) + box decode fused: lanes<32 issue priors/deltas loads at ENTRY
// (hidden under label group 0) and decode from registers at the end.
// Candidate emission via per-wave LDS queue + lane-parallel flush (R19).
// ---------------------------------------------------------------------------
__global__ __launch_bounds__(256) void k_filter(
    const float* __restrict__ labels, const float* __restrict__ deltas,
    const float* __restrict__ priors, unsigned char* __restrict__ bg,
    float4* __restrict__ boxes, int* __restrict__ cnt_g,
    u64* __restrict__ cand_g)
{
    __shared__ u64 sbuf[4][WBUF];
    int tid = threadIdx.x;
    int w = tid >> 6, lane = tid & 63;
    int wid = (blockIdx.x * 256 + tid) >> 6;
    int base = wid * 32;                      // 32 consecutive rows per wave
    if (base >= NROWS) return;                // uniform per wave

    // box-decode prefetch (lanes<32, one row each) -- hides under label phase
    int rdec = base + (lane & 31);
    int bdec = rdec / NN;
    int ndec = rdec - bdec * NN;
    float4 pr, dl;
    if (lane < 32) {
        pr = ((const float4*)priors)[ndec];
        dl = ((const float4*)deltas)[rdec];
    }

    u64* buf = sbuf[w];
    u64 ltmask = (lane == 63) ? 0x7FFFFFFFFFFFFFFFull : ((1ull << lane) - 1ull);
    int cnt = 0;                              // wave-uniform queue count

    u32 bgbits = 0;
    for (int g = 0; g < 4; ++g) {
        int r0 = base + g * 8;
        float va[8], vb[8];
        // load phase: 16 independent loads in flight, no branches
        #pragma unroll
        for (int j = 0; j < 8; ++j) {
            const float* L = labels + (size_t)(r0 + j) * CC;
            va[j] = L[lane];
            vb[j] = (lane < CC - 64) ? L[64 + lane] : -1.0f;
        }
        // process phase: register ops + ballots + rare LDS queue writes
        #pragma unroll
        for (int j = 0; j < 8; ++j) {
            int r = r0 + j;
            float L0 = __int_as_float(
                __builtin_amdgcn_readfirstlane(__float_as_int(va[j])));
            bool gt = (va[j] > L0) || (vb[j] > L0);   // vb=-1 for lanes>=17
            bool isbg = (__ballot(gt) == 0ull);       // argmax==0, 1st-idx rule
            bgbits |= (isbg ? 1u : 0u) << (g * 8 + j);
            float th1 = (lane == 0) ? T1C0 : T1;
            bool c1 = !isbg && (va[j] > th1);
            bool c2 = !isbg && (lane < CC - 64) && (vb[j] > T1);
            u64 m1 = __ballot(c1);
            u64 m2 = __ballot(c2);
            if (m1 | m2) {                            // uniform branch
                int tot = (int)(__popcll(m1) + __popcll(m2));
                if (cnt + tot > WBUF) {               // uniform overflow flush
                    for (int i = lane; i < cnt; i += 64) {
                        u64 e = buf[i];
                        float v = __uint_as_float((u32)(e >> 32));
                        u32 lo = (u32)e;
                        int c = (int)((lo >> 19) & 0x7F);
                        int rr = (int)(lo & 0x7FFFF);
                        int b = rr / NN;
                        int n = rr - b * NN;
                        int p = atomicAdd(&cnt_g[(b * CC + c) * PADI], 1);
                        if (p < CAND_CAP)
                            cand_g[(size_t)(b * CC + c) * CAND_CAP + p] =
                                pack_cand(v, n);
                    }
                    cnt = 0;
                }
                if (c1) {
                    int slot = cnt + (int)__popcll(m1 & ltmask);
                    buf[slot] = ((u64)__float_as_uint(va[j]) << 32)
                              | ((u64)lane << 19) | (u32)r;
                }
                if (c2) {
                    int slot = cnt + (int)__popcll(m1)
                             + (int)__popcll(m2 & ltmask);
                    buf[slot] = ((u64)__float_as_uint(vb[j]) << 32)
                              | ((u64)(64 + lane) << 19) | (u32)r;
                }
                cnt += tot;
            }
        }
    }
    // final lane-parallel flush: one atomic instruction per 64 entries
    for (int i = lane; i < cnt; i += 64) {
        u64 e = buf[i];
        float v = __uint_as_float((u32)(e >> 32));
        u32 lo = (u32)e;
        int c = (int)((lo >> 19) & 0x7F);
        int rr = (int)(lo & 0x7FFFF);
        int b = rr / NN;
        int n = rr - b * NN;
        int p = atomicAdd(&cnt_g[(b * CC + c) * PADI], 1);
        if (p < CAND_CAP)
            cand_g[(size_t)(b * CC + c) * CAND_CAP + p] = pack_cand(v, n);
    }
    // coalesced bg write: lane l<8 packs 4 rows' bytes into one u32
    if (lane < 8) {
        u32 wv = 0;
        #pragma unroll
        for (int j = 0; j < 4; ++j)
            wv |= ((bgbits >> (4 * lane + j)) & 1u) << (8 * j);
        *(u32*)(bg + base + 4 * lane) = wv;
    }

    // box decode epilogue (exact numpy op order, FMA-free), from registers
    if (lane < 32) {
        float ph  = __fsub_rn(pr.z, pr.x);
        float pw  = __fsub_rn(pr.w, pr.y);
        float pcy = __fadd_rn(pr.x, __fmul_rn(0.5f, ph));
        float pcx = __fadd_rn(pr.y, __fmul_rn(0.5f, pw));
        float d0 = __fmul_rn(dl.x, 0.1f);
        float d1 = __fmul_rn(dl.y, 0.1f);
        float d2 = __fmul_rn(dl.z, 0.2f);
        float d3 = __fmul_rn(dl.w, 0.2f);
        float cy = __fadd_rn(__fmul_rn(d0, ph), pcy);
        float cx = __fadd_rn(__fmul_rn(d1, pw), pcx);
        float hh = __fmul_rn(expf(d2), ph);
        float ww = __fmul_rn(expf(d3), pw);
        float h2 = __fmul_rn(hh, 0.5f);
        float w2 = __fmul_rn(ww, 0.5f);
        float y1 = fminf(fmaxf(__fsub_rn(cy, h2), 0.0f), 1.0f);
        float x1 = fminf(fmaxf(__fsub_rn(cx, w2), 0.0f), 1.0f);
        float y2 = fminf(fmaxf(__fadd_rn(cy, h2), 0.0f), 1.0f);
        float x2 = fminf(fmaxf(__fadd_rn(cx, w2), 0.0f), 1.0f);
        boxes[rdec] = make_float4(y1, x1, y2, x2);
    }
}

// ---------------------------------------------------------------------------
// Kernel 2: per-(b,c) sorted-scan greedy NMS. 256 threads. (unchanged)
// ---------------------------------------------------------------------------
__global__ __launch_bounds__(256) void k_nms(
    const float* __restrict__ labels, const unsigned char* __restrict__ bg,
    const float4* __restrict__ boxes, const int* __restrict__ cnt_g,
    const u64* __restrict__ cand_g,
    float* __restrict__ out_s, int* __restrict__ out_i)
{
    __shared__ u64 arr[CAND_CAP];
    __shared__ float4 sbox[CHUNK];
    __shared__ float ks[KK];
    __shared__ int   ki[KK];
    __shared__ int s_kept, s_cnt;

    int bc = blockIdx.x, tid = threadIdx.x;
    int b = bc / CC, c = bc - b * CC;
    float thrc = (c == 0) ? T1C0 : T1;
    const float4* bxb = boxes + (size_t)b * NN;

    int gcnt = cnt_g[bc * PADI];
    bool ovf = gcnt > CAND_CAP;
    int cnt0 = ovf ? 0 : gcnt;
    for (int i = tid; i < CAND_CAP; i += 256)
        arr[i] = (i < cnt0) ? cand_g[(size_t)bc * CAND_CAP + i] : 0ull;
    if (tid == 0) { s_kept = 0; s_cnt = cnt0; }
    __syncthreads();

    float4 kb = make_float4(0.f, 0.f, 0.f, 0.f);
    float  ka = 0.0f;
    float hi = ovf ? 1.0001f : thrc;
    float bw = TIER_W;
    bool first = !ovf;

    while (true) {
        if (!first) {
            if (s_kept >= KK || hi <= 0.5f) break;
            float lo = fmaxf(hi - bw, 0.5f);
            if (tid == 0) s_cnt = 0;
            __syncthreads();
            const float* lab = labels + (size_t)b * NN * CC + c;
            const unsigned char* bgb = bg + (size_t)b * NN;
            for (int n = tid; n < NN; n += 256) {
                float v = lab[(size_t)n * CC];
                if (v > lo && v <= hi && v > 0.5f && !bgb[n]) {
                    int p = atomicAdd(&s_cnt, 1);
                    if (p < CAND_CAP) arr[p] = pack_cand(v, n);
                }
            }
            __syncthreads();
            if (s_cnt > CAND_CAP && bw > 1e-7f) {  // band overflow: shrink, retry
                bw *= 0.5f;
                __syncthreads();
                continue;
            }
            int c2 = min(s_cnt, CAND_CAP);
            for (int i = tid; i < CAND_CAP; i += 256)
                if (i >= c2) arr[i] = 0ull;
            hi = lo;
            bw = TIER_W;
            __syncthreads();
        }
        first = false;

        int cs = min(s_cnt, CAND_CAP);
        if (cs <= 128)      bitonic_desc<128, 256>(arr, tid);  // uniform branch
        else if (cs <= 256) bitonic_desc<256, 256>(arr, tid);
        else                bitonic_desc<CAND_CAP, 256>(arr, tid);

        // chunked stage + scan: most blocks finish in the first 128
        for (int ch0 = 0; ch0 < cs; ch0 += CHUNK) {
            if (s_kept >= KK) break;                       // uniform (post-sync)
            int che = min(ch0 + CHUNK, cs);
            for (int i = ch0 + tid; i < che; i += 256) {
                int n = (int)(~(u32)arr[i]);
                if ((u32)n < (u32)NN) sbox[i - ch0] = bxb[n];  // guarded
            }
            __syncthreads();
            if (tid < 64) {                    // wave 0: serial greedy scan
                int kept = s_kept;
                for (int i = ch0; i < che; ++i) {
                    u64 key = arr[i];
                    float sc = __uint_as_float((u32)(key >> 32));
                    int n = (int)(~(u32)key);
                    float4 cb = sbox[i - ch0];
                    float a1 = __fmul_rn(__fsub_rn(cb.z, cb.x), __fsub_rn(cb.w, cb.y));
                    bool sup = false;
                    if (tid < kept) {
                        float iy1 = fmaxf(kb.x, cb.x);
                        float ix1 = fmaxf(kb.y, cb.y);
                        float iy2 = fminf(kb.z, cb.z);
                        float ix2 = fminf(kb.w, cb.w);
                        float ih = fmaxf(__fsub_rn(iy2, iy1), 0.0f);
                        float iw = fmaxf(__fsub_rn(ix2, ix1), 0.0f);
                        float inter = __fmul_rn(ih, iw);
                        float den = __fadd_rn(__fsub_rn(__fadd_rn(ka, a1), inter), 1e-8f);
                        sup = __fdiv_rn(inter, den) > 0.5f;
                    }
                    if (__ballot(sup) == 0ull) {
                        if (tid == kept) { kb = cb; ka = a1; }
                        if (tid == 0)    { ks[kept] = sc; ki[kept] = n; }
                        ++kept;
                        if (kept == KK) break;
                    }
                }
                if (tid == 0) s_kept = kept;
            }
            __syncthreads();
        }
    }

    int kept = min(s_kept, KK);
    for (int k = tid; k < KK; k += 256) {
        out_s[(size_t)bc * KK + k] = (k < kept) ? ks[k] : 0.0f;
        out_i[(size_t)bc * KK + k] = (k < kept) ? ki[k] : 0;
    }
}

// ---------------------------------------------------------------------------
// Kernel 3a: per-(batch, 512-chunk) partial top-200. Grid = BB*8 blocks.
// ---------------------------------------------------------------------------
__global__ __launch_bounds__(256) void k_topk1(
    const float* __restrict__ nms_s, u64* __restrict__ topA)
{
    __shared__ u64 arr[512];
    int bchunk = blockIdx.x;
    int b = bchunk >> 3, ch = bchunk & 7;
    int tid = threadIdx.x;
    int base = ch * 512;
    for (int i = tid; i < 512; i += 256) {
        int fp = base + i;
        u64 v = 0ull;
        if (fp < CC * KK) {
            float s = nms_s[(size_t)b * CC * KK + fp];
            v = ((u64)__float_as_uint(s) << 32) | (u32)(~(u32)fp);
        }
        arr[i] = v;
    }
    __syncthreads();
    bitonic_desc<512, 256>(arr, tid);
    if (tid < MT) topA[(size_t)bchunk * MT + tid] = arr[tid];
}

// ---------------------------------------------------------------------------
// Kernel 3b: per-batch merge of 8x200 -> stable top-200 + output assembly.
// ---------------------------------------------------------------------------
__global__ __launch_bounds__(512) void k_topk2(
    const u64* __restrict__ topA, const int* __restrict__ nms_i,
    const float4* __restrict__ boxes, float* __restrict__ out)
{
    __shared__ u64 arr[2048];
    __shared__ int s_vc;
    int b = blockIdx.x, tid = threadIdx.x;
    for (int i = tid; i < 2048; i += 512)
        arr[i] = (i < 8 * MT) ? topA[(size_t)b * 8 * MT + i] : 0ull;
    if (tid == 0) s_vc = 0;
    __syncthreads();

    bitonic_desc<2048, 512>(arr, tid);

    if (tid < MT) {
        u64 key = arr[tid];
        float sc = __uint_as_float((u32)(key >> 32));
        int fp = (int)(~(u32)key);
        bool valid = sc > 0.0f;
        float4 bb = make_float4(0.f, 0.f, 0.f, 0.f);
        float cls = 0.0f;
        if (valid) {
            int aidx = nms_i[(size_t)b * CC * KK + fp];
            bb = boxes[(size_t)b * NN + aidx];
            cls = (float)(fp / KK);
        }
        ((float4*)out)[(size_t)b * MT + tid] = bb;
        out[(size_t)BB * MT * 4 + (size_t)b * MT + tid] = sc;
        out[(size_t)BB * MT * 5 + (size_t)b * MT + tid] = cls;
        if (valid) atomicAdd(&s_vc, 1);
    }
    __syncthreads();
    if (tid == 0) out[(size_t)BB * MT * 6 + b] = (float)s_vc;
}

// ---------------------------------------------------------------------------
extern "C" void kernel_launch(void* const* d_in, const int* in_sizes, int n_in,
                              void* d_out, int out_size, void* d_ws, size_t ws_size,
                              hipStream_t stream)
{
    const float* deltas = (const float*)d_in[0];
    const float* labels = (const float*)d_in[1];
    const float* priors = (const float*)d_in[2];
    float* out = (float*)d_out;

    char* ws = (char*)d_ws;
    size_t off = 0;
    float4* boxes = (float4*)(ws + off);            off += (size_t)NROWS * 16;
    unsigned char* bg = (unsigned char*)(ws + off); off += ((size_t)NROWS + 127) & ~127ull;
    int* cnt_g = (int*)(ws + off);                  off += (size_t)BB * CC * PADI * 4;
    u64* cand_g = (u64*)(ws + off);                 off += (size_t)BB * CC * CAND_CAP * 8;
    float* nms_s = (float*)(ws + off);              off += (size_t)BB * CC * KK * 4;
    int* nms_i = (int*)(ws + off);                  off += (size_t)BB * CC * KK * 4;
    u64* topA = (u64*)(ws + off);                   off += (size_t)BB * 8 * MT * 8;

    k_zero<<<(BB * CC + 255) / 256, 256, 0, stream>>>(cnt_g);
    k_filter<<<(NROWS / 32 + 3) / 4, 256, 0, stream>>>(labels, deltas, priors,
                                                       bg, boxes, cnt_g, cand_g);
    k_nms<<<BB * CC, 256, 0, stream>>>(labels, bg, boxes, cnt_g, cand_g, nms_s, nms_i);
    k_topk1<<<BB * 8, 256, 0, stream>>>(nms_s, topA);
    k_topk2<<<BB, 512, 0, stream>>>(topA, nms_i, boxes, out);
}